// Round 4
// baseline (280.892 us; speedup 1.0000x reference)
//
#include <hip/hip_runtime.h>
#include <hip/hip_bf16.h>

#define DF   128      // feature dim
#define DPC  16       // dims per capsule (8 caps)
#define KCAP 62       // slots per 128B bucket row: [u32 count | 62 ushort src]
#define RWRD 32       // bucket row size in u32 words (128 B)

#define NB_ROUTE 2048 // persistent route WGs: 8/CU x 256 CU (VGPR<=64 tier)
#define NB_PREP  2048 // persistent prep WGs
#define NB_ZERO  257  // detect (1) + zeroing (256)

// ---------- helpers ----------
__device__ __forceinline__ float cap_sum(float v) {   // sum over lanes l..l|7
    v += __shfl_xor(v, 1);
    v += __shfl_xor(v, 2);
    v += __shfl_xor(v, 4);
    return v;
}
__device__ __forceinline__ float bits_lo(unsigned int w) {
    union { unsigned int u; float f; } c; c.u = w << 16; return c.f;
}
__device__ __forceinline__ float bits_hi(unsigned int w) {
    union { unsigned int u; float f; } c; c.u = w & 0xFFFF0000u; return c.f;
}
__device__ __forceinline__ unsigned int f2b_pack(float lo, float hi) {
    __hip_bfloat16 a = __float2bfloat16(lo), b = __float2bfloat16(hi);
    unsigned short ua = *reinterpret_cast<unsigned short*>(&a);
    unsigned short ub = *reinterpret_cast<unsigned short*>(&b);
    return ((unsigned int)ub << 16) | ua;
}
__device__ __forceinline__ float2 load_x2(const void* __restrict__ xraw, int fp32,
                                          int node, int lane) {
    size_t off = (size_t)node * DF + (size_t)lane * 2;
    if (fp32) {
        return *reinterpret_cast<const float2*>((const float*)xraw + off);
    } else {
        unsigned int w = ((const unsigned int*)xraw)[(size_t)node * 64 + lane];
        return make_float2(bits_lo(w), bits_hi(w));
    }
}
__device__ __forceinline__ int2 edge_st(const int* __restrict__ ei, int i64,
                                        int e, int n_edges) {
    size_t si = i64 ? (size_t)2 * e             : (size_t)e;
    size_t ti = i64 ? (size_t)2 * (n_edges + e) : (size_t)(n_edges + e);
    return make_int2(ei[si], ei[ti]);
}
// per-chunk routing math on PACKED bf16 words (no z[16] expansion: each word
// is unpacked twice -> ~16 extra VALU/chunk but 16 fewer live VGPRs, which
// keeps the whole kernel under the 64-VGPR tier with zero scratch spills).
// Op order identical to the original cvt16+loops version -> same numerics.
__device__ __forceinline__ void proc_pk(const uint4& w0, const uint4& w1,
                                        bool valid, const float* u, float* acc) {
    unsigned ww[8] = {w0.x, w0.y, w0.z, w0.w, w1.x, w1.y, w1.z, w1.w};
    float p = 0.0f;
    #pragma unroll
    for (int q = 0; q < 8; ++q) {
        p = fmaf(bits_lo(ww[q]), u[2*q],   p);
        p = fmaf(bits_hi(ww[q]), u[2*q+1], p);
    }
    float ex = __expf(p);
    float sd = ex;
    sd += __shfl_xor(sd, 1);
    sd += __shfl_xor(sd, 2);
    sd += __shfl_xor(sd, 4);
    float w = valid ? ex * __builtin_amdgcn_rcpf(sd) : 0.0f;
    #pragma unroll
    for (int q = 0; q < 8; ++q) {
        acc[2*q]   = fmaf(w, bits_lo(ww[q]), acc[2*q]);
        acc[2*q+1] = fmaf(w, bits_hi(ww[q]), acc[2*q+1]);
    }
}

// ---------- 1: detect dtypes (block 0) + zero bucket rows (blocks 1..) ------
__global__ void k_detect_zero(const unsigned int* __restrict__ xw,
                              const unsigned int* __restrict__ ew,
                              int* __restrict__ flags, int* __restrict__ bkt,
                              int n_nodes) {
    if (blockIdx.x == 0) {
        __shared__ int s_nan, s_zero;
        int tid = threadIdx.x;
        if (tid == 0) { s_nan = 0; s_zero = 0; }
        __syncthreads();
        int cnt_nan = 0;
        for (int i = tid; i < 4096; i += 256) {       // P(fp32 miss) ~ e^-16
            unsigned int lo = xw[i] & 0xFFFFu;
            if ((lo & 0x7F80u) == 0x7F80u) cnt_nan++; // impossible in bf16 data
        }
        int cnt_zero = 0;
        for (int i = tid; i < 1024; i += 256) {
            if (ew[2 * i + 1] == 0u) cnt_zero++;      // int64 high words zero
        }
        atomicAdd(&s_nan, cnt_nan);
        atomicAdd(&s_zero, cnt_zero);
        __syncthreads();
        if (tid == 0) {
            flags[0] = (s_nan > 0) ? 1 : 0;   // x is fp32
            flags[1] = (s_zero > 512) ? 1 : 0; // edge_index is int64
        }
    } else {
        int total = n_nodes * (RWRD / 4);             // uint4 per all rows
        int stride = (NB_ZERO - 1) * 256;
        for (int i = (blockIdx.x - 1) * 256 + threadIdx.x; i < total; i += stride)
            reinterpret_cast<uint4*>(bkt)[i] = make_uint4(0u, 0u, 0u, 0u);
    }
}

// ---------- 2: fused xc(bf16, swizzled) + single-pass bucketing -------------
// Round-4 change: the slot write is now an atomicOr of the ushort into its
// 32-bit word. Rationale (round-0..3 evidence: edge phase stuck at ~110 us):
// normal stores acquire the bucket line DIRTY in one XCD's private L2, and
// the next count-atomic (an LLC-point op) from another XCD must probe/flush
// it -> ~32 ownership migrations per line x 50000 lines across 8 incoherent
// XCDs. With atomicOr, EVERY touch of a bucket line is performed at the LLC:
// no L2 ownership ping-pong, just pipelined same-line LLC ops.
// Correctness: atomicAdd hands out unique slots, so each ushort half-word is
// OR'd exactly once into a pre-zeroed row == plain store.
__global__ void k_prep(const void* __restrict__ xraw, unsigned int* __restrict__ xcb,
                       const int* __restrict__ ei, int* __restrict__ bkt,
                       const int* __restrict__ flags,
                       int n_nodes, int n_edges) {
    const int fp32 = flags[0];
    const int lane = threadIdx.x & 63;
    const int gw   = (blockIdx.x * blockDim.x + threadIdx.x) >> 6;
    const int nw   = (gridDim.x * blockDim.x) >> 6;

    for (int wid = gw; wid < n_nodes; wid += nw) {
        float2 v = load_x2(xraw, fp32, wid, lane);
        float ss = cap_sum(v.x * v.x + v.y * v.y);
        float scale = 1.0f / fmaxf(sqrtf(ss), 1e-12f);
        int c = lane >> 3, jp = lane & 7;
        int w = (jp < 4) ? (c * 4 + jp) : (32 + c * 4 + (jp - 4));
        xcb[(size_t)wid * 64 + w] = f2b_pack(v.x * scale, v.y * scale);
    }

    const int i64 = flags[1];
    const int gtid = blockIdx.x * blockDim.x + threadIdx.x;
    const int gth  = gridDim.x * blockDim.x;
    for (int e = gtid; e < n_edges; e += gth) {
        int2 st = edge_st(ei, i64, e, n_edges);
        if ((unsigned)st.x < (unsigned)n_nodes &&
            (unsigned)st.y < (unsigned)n_nodes) {
            unsigned* row = (unsigned*)(bkt + (size_t)st.y * RWRD);
            int slot = atomicAdd((int*)row, 1);
            if (slot < KCAP) {
                int us   = 2 + slot;                       // ushort index in row
                unsigned val = (unsigned)(unsigned short)st.x << (16 * (us & 1));
                atomicOr(row + (us >> 1), val);            // LLC-point write
            }
        }
    }
}

// ---------- 3: fused 3-iteration routing ----------
// One wave per target node, persistent (no barriers -> waves independent).
// Lane = e8*8 + c: 8 edge slots x 8 capsules.
//
// Round-4 structure: NO register chunk-cache (rounds 1-3 proved the allocator
// stays on the 64-VGPR tier and spills it to HBM scratch). Instead the <=3
// chunks are RELOADED from cache each iteration (xcb = 12.8 MB, LLC-resident;
// addresses live in 3 VGPRs computed once via the shfl-row trick), with
// staged upfront issue so latency overlaps compute. The asm memory clobber at
// each iteration top stops the compiler from CSE-ing the reloads back into
// long-lived registers (which would re-create the spill). Packed processing
// keeps the peak live set ~58 VGPRs -> no scratch.
__global__ void __launch_bounds__(256)
k_route(const int* __restrict__ bkt,
        const unsigned int* __restrict__ xcb,
        float* __restrict__ u_out, int n_nodes) {
    const int lane = threadIdx.x & 63;
    const int gw   = (blockIdx.x * blockDim.x + threadIdx.x) >> 6;
    const int nw   = (gridDim.x * blockDim.x) >> 6;
    const int e8 = lane >> 3;
    const int c  = lane & 7;
    const int coff = c * 16;     // byte offset within each 128 B half
    const char* __restrict__ xb = (const char*)xcb;

    for (int t = gw; t < n_nodes; t += nw) {
        // --- 1 coalesced load: whole bucket row, word (lane&31) per lane ---
        unsigned rw = ((const unsigned*)(bkt + (size_t)t * RWRD))[lane & 31];

        // --- target row loads issued while the row load is in flight ---
        size_t trow = (size_t)t << 8;
        uint4 t0 = *reinterpret_cast<const uint4*>(xb + trow + coff);
        uint4 t1 = *reinterpret_cast<const uint4*>(xb + trow + 128 + coff);

        int deg = __builtin_amdgcn_readfirstlane((int)rw); // lane0 = count
        deg = min(deg, KCAP);

        // neighbor id of slot s: ushort at row byte 4+2s, via shfl from the
        // lane holding that word (row replicated in lanes 0..31 / 32..63).
        auto nid = [&](int s) -> int {
            int g = 4 + 2 * s;                   // byte offset in row
            unsigned wv = __shfl(rw, (lane & 32) | (g >> 2));
            return (int)((g & 2) ? (wv >> 16) : (wv & 0xFFFFu));
        };

        // per-lane chunk base offsets, computed ONCE (3 VGPRs)
        int off0 = 0, off1 = 0, off2 = 0;
        {
            int s0 = e8,      c0 = (s0 < deg) ? s0 : 0;
            int s1 = e8 + 8,  c1 = (s1 < deg) ? s1 : 0;
            int s2 = e8 + 16, c2 = (s2 < deg) ? s2 : 0;
            if (deg > 0)  off0 = nid(c0) << 8;
            if (deg > 8)  off1 = nid(c1) << 8;
            if (deg > 16) off2 = nid(c2) << 8;
        }

        // --- normalize target capsule (keep only packed tw[] + sc live) ---
        unsigned tw[8] = {t0.x, t0.y, t0.z, t0.w, t1.x, t1.y, t1.z, t1.w};
        float ss = 0.0f;
        #pragma unroll
        for (int q = 0; q < 8; ++q) {
            float xl = bits_lo(tw[q]), xh = bits_hi(tw[q]);
            ss = fmaf(xl, xl, ss);
            ss = fmaf(xh, xh, ss);
        }
        float sc = __builtin_amdgcn_rsqf(fmaxf(ss, 1e-24f));
        float u[DPC];
        #pragma unroll
        for (int q = 0; q < 8; ++q) {
            u[2*q]   = bits_lo(tw[q]) * sc;
            u[2*q+1] = bits_hi(tw[q]) * sc;
        }

        for (int it = 0; it < 3; ++it) {
            // stop load-CSE across iterations (would re-create the spill)
            asm volatile("" ::: "memory");

            uint4 a0, b0, a1, b1, a2, b2;
            if (deg > 0) {   // issue chunks 0,1 back-to-back
                a0 = *reinterpret_cast<const uint4*>(xb + off0 + coff);
                b0 = *reinterpret_cast<const uint4*>(xb + off0 + 128 + coff);
            }
            if (deg > 8) {
                a1 = *reinterpret_cast<const uint4*>(xb + off1 + coff);
                b1 = *reinterpret_cast<const uint4*>(xb + off1 + 128 + coff);
            }
            float acc[DPC];
            #pragma unroll
            for (int j = 0; j < DPC; ++j) acc[j] = 0.0f;

            if (deg > 0)  proc_pk(a0, b0, e8 < deg, u, acc);
            if (deg > 16) {  // issue chunk 2 under chunk-0/1 compute
                a2 = *reinterpret_cast<const uint4*>(xb + off2 + coff);
                b2 = *reinterpret_cast<const uint4*>(xb + off2 + 128 + coff);
            }
            if (deg > 8)  proc_pk(a1, b1, 8  + e8 < deg, u, acc);
            if (deg > 16) proc_pk(a2, b2, 16 + e8 < deg, u, acc);
            if (deg > 24) {                  // rare tail: stream per iteration
                for (int base = 24; base < deg; base += 8) {
                    int s  = base + e8;
                    int sl = (s < deg) ? s : 0;
                    int off = nid(sl) << 8;
                    uint4 a = *reinterpret_cast<const uint4*>(xb + off + coff);
                    uint4 b = *reinterpret_cast<const uint4*>(xb + off + 128 + coff);
                    proc_pk(a, b, s < deg, u, acc);
                }
            }

            // reduce across the 8 edge slots (lane bits 3..5)
            #pragma unroll
            for (int j = 0; j < DPC; ++j) {
                acc[j] += __shfl_xor(acc[j], 8);
                acc[j] += __shfl_xor(acc[j], 16);
                acc[j] += __shfl_xor(acc[j], 32);
            }
            // residual + per-capsule l2norm; xt recomputed from tw,sc
            // (identical ops/values as keeping xt[16] live)
            float s2 = 0.0f;
            #pragma unroll
            for (int q = 0; q < 8; ++q) {
                float xl = bits_lo(tw[q]) * sc;
                float xh = bits_hi(tw[q]) * sc;
                u[2*q]   = acc[2*q]   + xl;
                u[2*q+1] = acc[2*q+1] + xh;
                s2 = fmaf(u[2*q],   u[2*q],   s2);
                s2 = fmaf(u[2*q+1], u[2*q+1], s2);
            }
            float sc2 = __builtin_amdgcn_rsqf(fmaxf(s2, 1e-24f));
            #pragma unroll
            for (int j = 0; j < DPC; ++j) u[j] *= sc2;
        }

        if (e8 == 0) {  // lanes 0..7 cover the full 512 B fp32 output row
            float* dst = u_out + (size_t)t * DF + c * DPC;
            #pragma unroll
            for (int j = 0; j < DPC; j += 4)
                *reinterpret_cast<float4*>(dst + j) =
                    make_float4(u[j], u[j+1], u[j+2], u[j+3]);
        }
    }
}

extern "C" void kernel_launch(void* const* d_in, const int* in_sizes, int n_in,
                              void* d_out, int out_size, void* d_ws, size_t ws_size,
                              hipStream_t stream) {
    const void* x  = d_in[0];
    const int*  ei = (const int*)d_in[1];
    const int n_nodes = in_sizes[0] / DF;        // 50000
    const int n_edges = in_sizes[1] / 2;         // 800000
    const size_t NC = (size_t)n_nodes * DF;

    // ws: xcb bf16[12.8MB] | bucket rows[n*128B, 6.4MB] | flags[2]  (~19.2MB)
    unsigned int* xcb = (unsigned int*)d_ws;
    int* bkt   = (int*)(xcb + NC / 2);
    int* flags = bkt + (size_t)n_nodes * RWRD;

    float* u_out = (float*)d_out;

    k_detect_zero<<<NB_ZERO, 256, 0, stream>>>(
        (const unsigned int*)x, (const unsigned int*)ei, flags, bkt, n_nodes);
    k_prep<<<NB_PREP, 256, 0, stream>>>(x, xcb, ei, bkt, flags,
                                        n_nodes, n_edges);
    k_route<<<NB_ROUTE, 256, 0, stream>>>(bkt, xcb, u_out, n_nodes);
}

// Round 5
// 262.665 us; speedup vs baseline: 1.0694x; 1.0694x over previous
//
#include <hip/hip_runtime.h>
#include <hip/hip_bf16.h>

#define DF   128      // feature dim
#define DPC  16       // dims per capsule (8 caps)
#define KCAP 64       // slots per 128B row (count lives in separate cnt array)

#define NB_XC    2048 // persistent xc WGs
#define NB_BKT   2048 // persistent bucket WGs
#define NB_ROUTE 1536 // 6 WG/CU x 256 CU (LDS 25KB/WG -> 6 resident/CU)
#define NB_ZERO  64   // detect (1) + cnt zeroing (63)

// ---------- helpers ----------
__device__ __forceinline__ float cap_sum(float v) {   // sum over lanes l..l|7
    v += __shfl_xor(v, 1);
    v += __shfl_xor(v, 2);
    v += __shfl_xor(v, 4);
    return v;
}
__device__ __forceinline__ float bits_lo(unsigned int w) {
    union { unsigned int u; float f; } c; c.u = w << 16; return c.f;
}
__device__ __forceinline__ float bits_hi(unsigned int w) {
    union { unsigned int u; float f; } c; c.u = w & 0xFFFF0000u; return c.f;
}
__device__ __forceinline__ unsigned int f2b_pack(float lo, float hi) {
    __hip_bfloat16 a = __float2bfloat16(lo), b = __float2bfloat16(hi);
    unsigned short ua = *reinterpret_cast<unsigned short*>(&a);
    unsigned short ub = *reinterpret_cast<unsigned short*>(&b);
    return ((unsigned int)ub << 16) | ua;
}
__device__ __forceinline__ float2 load_x2(const void* __restrict__ xraw, int fp32,
                                          int node, int lane) {
    size_t off = (size_t)node * DF + (size_t)lane * 2;
    if (fp32) {
        return *reinterpret_cast<const float2*>((const float*)xraw + off);
    } else {
        unsigned int w = ((const unsigned int*)xraw)[(size_t)node * 64 + lane];
        return make_float2(bits_lo(w), bits_hi(w));
    }
}
// per-chunk routing math on PACKED bf16 words (each word unpacked twice ->
// ~16 extra VALU/chunk but 16 fewer live VGPRs; keeps the kernel in the
// 64-VGPR/8-wave tier). Op order identical to the cvt16 version -> same
// numerics as all previous rounds.
__device__ __forceinline__ void proc_pk(const uint4& w0, const uint4& w1,
                                        bool valid, const float* u, float* acc) {
    unsigned ww[8] = {w0.x, w0.y, w0.z, w0.w, w1.x, w1.y, w1.z, w1.w};
    float p = 0.0f;
    #pragma unroll
    for (int q = 0; q < 8; ++q) {
        p = fmaf(bits_lo(ww[q]), u[2*q],   p);
        p = fmaf(bits_hi(ww[q]), u[2*q+1], p);
    }
    float ex = __expf(p);
    float sd = ex;
    sd += __shfl_xor(sd, 1);
    sd += __shfl_xor(sd, 2);
    sd += __shfl_xor(sd, 4);
    float w = valid ? ex * __builtin_amdgcn_rcpf(sd) : 0.0f;
    #pragma unroll
    for (int q = 0; q < 8; ++q) {
        acc[2*q]   = fmaf(w, bits_lo(ww[q]), acc[2*q]);
        acc[2*q+1] = fmaf(w, bits_hi(ww[q]), acc[2*q+1]);
    }
}

// ---------- 1: detect dtypes (block 0) + zero cnt array (blocks 1..) --------
// Slot rows no longer need zeroing (every slot < deg is written exactly once
// by k_bucket; route never reads past deg).
__global__ void k_detect_zero(const unsigned int* __restrict__ xw,
                              const unsigned int* __restrict__ ew,
                              int* __restrict__ flags, int* __restrict__ cnt,
                              int zwords) {
    if (blockIdx.x == 0) {
        __shared__ int s_nan, s_zero;
        int tid = threadIdx.x;
        if (tid == 0) { s_nan = 0; s_zero = 0; }
        __syncthreads();
        int cnt_nan = 0;
        for (int i = tid; i < 4096; i += 256) {       // P(fp32 miss) ~ e^-16
            unsigned int lo = xw[i] & 0xFFFFu;
            if ((lo & 0x7F80u) == 0x7F80u) cnt_nan++; // impossible in bf16 data
        }
        int cnt_zero = 0;
        for (int i = tid; i < 1024; i += 256) {
            if (ew[2 * i + 1] == 0u) cnt_zero++;      // int64 high words zero
        }
        atomicAdd(&s_nan, cnt_nan);
        atomicAdd(&s_zero, cnt_zero);
        __syncthreads();
        if (tid == 0) {
            flags[0] = (s_nan > 0) ? 1 : 0;   // x is fp32
            flags[1] = (s_zero > 512) ? 1 : 0; // edge_index is int64
        }
    } else {
        int stride = (NB_ZERO - 1) * 256;
        for (int i = (blockIdx.x - 1) * 256 + threadIdx.x; i < zwords; i += stride)
            cnt[i] = 0;
    }
}

// ---------- 2a: xc = per-capsule l2norm of x, packed bf16, swizzled ---------
// xc row (256 B): words [0,32) = caps' dims 0..7 (4 words/cap),
//                 words [32,64) = caps' dims 8..15.
__global__ void k_xc(const void* __restrict__ xraw,
                     unsigned int* __restrict__ xcb,
                     const int* __restrict__ flags, int n_nodes) {
    const int fp32 = flags[0];
    const int lane = threadIdx.x & 63;
    const int gw   = (blockIdx.x * blockDim.x + threadIdx.x) >> 6;
    const int nw   = (gridDim.x * blockDim.x) >> 6;
    for (int wid = gw; wid < n_nodes; wid += nw) {
        float2 v = load_x2(xraw, fp32, wid, lane);
        float ss = cap_sum(v.x * v.x + v.y * v.y);
        float scale = 1.0f / fmaxf(sqrtf(ss), 1e-12f);
        int cc = lane >> 3, jp = lane & 7;
        int w = (jp < 4) ? (cc * 4 + jp) : (32 + cc * 4 + (jp - 4));
        xcb[(size_t)wid * 64 + w] = f2b_pack(v.x * scale, v.y * scale);
    }
}

// ---------- 2b: bucketing with atomics ISOLATED from stores -----------------
// Round-5 hypothesis test. r0-r4 put the count atomic and the slot stores in
// the SAME cache line: every LLC-point atomic had to snoop/flush the line
// just dirtied by some XCD's store -> per-edge flush round trips. Now:
//   * cnt[t*32]: dedicated atomic-ONLY lines (1 count / 128 B line, same
//     atomic density per line as r0) -> pure pipelined LLC adds, no flushes.
//   * rows[t*64+slot]: store-ONLY lines -> fire-and-forget into the local
//     XCD L2 (byte-granular dirty merge at end-of-kernel writeback; route
//     runs in a later kernel so visibility is guaranteed).
// One atomic per edge (r4's atomicOr doubled the LLC line-ops and regressed).
__global__ void k_bucket(const int* __restrict__ ei,
                         int* __restrict__ cnt, int cstr,
                         unsigned short* __restrict__ rows,
                         const int* __restrict__ flags,
                         int n_nodes, int n_edges) {
    const int i64 = flags[1];
    const int gtid = blockIdx.x * blockDim.x + threadIdx.x;
    const int gth  = gridDim.x * blockDim.x;
    for (int e = gtid; e < n_edges; e += gth) {
        int s, t;
        if (i64) {   // coalesced 8B loads, keep low words
            long sv = ((const long*)ei)[e];
            long tv = ((const long*)ei)[(size_t)n_edges + e];
            s = (int)sv; t = (int)tv;
        } else {
            s = ei[e]; t = ei[(size_t)n_edges + e];
        }
        if ((unsigned)s < (unsigned)n_nodes && (unsigned)t < (unsigned)n_nodes) {
            int slot = atomicAdd(cnt + (size_t)t * cstr, 1);
            if (slot < KCAP)
                rows[(size_t)t * KCAP + slot] = (unsigned short)s;
        }
    }
}

// ---------- 3: fused 3-iteration routing, LDS-staged chunks -----------------
// One wave per target node, persistent, 1536 WGs (6/CU: LDS-capped).
// Lane = e8*8 + c: 8 edge slots x 8 capsules.
//
// Round-5 structure: neighbor rows are touched in GLOBAL memory exactly once
// per node -- staged into wave-private LDS via global_load_lds (width 16,
// per-lane global src, linear LDS dest = base + lane*16, the HW contract),
// then all 3 iterations re-read them from LDS (contiguous 16B/lane
// ds_read_b128 = conflict-free). This needs no long-lived chunk registers
// (r1/r3: spilled at the 64-VGPR tier) and no per-iteration global reloads
// (r4: latency-exposed at 4 waves/SIMD). waves_per_eu(8) pins the allocator
// to <=64 VGPR; LDS 25KB/WG caps residency at 6 WG/CU = 24 waves/CU.
__global__ void __launch_bounds__(256)
__attribute__((amdgpu_waves_per_eu(8)))
k_route(const unsigned short* __restrict__ rows,
        const unsigned int* __restrict__ xcb,
        const int* __restrict__ cnt, int cstr,
        float* __restrict__ u_out, int n_nodes) {
    __shared__ char smem[4 * 6144];      // 4 waves x 3 chunks x 2KB
    const int lane = threadIdx.x & 63;
    char* wbase = smem + (threadIdx.x >> 6) * 6144;
    const int gw = (blockIdx.x * blockDim.x + threadIdx.x) >> 6;
    const int nw = (gridDim.x * blockDim.x) >> 6;
    const int e8 = lane >> 3;
    const int c  = lane & 7;
    const int coff = c * 16;             // byte offset within each 128 B half
    const char* __restrict__ xb = (const char*)xcb;

    for (int t = gw; t < n_nodes; t += nw) {
        // one coalesced line: 64 slot ushorts (32 words, replicated halves)
        const unsigned* wrow = (const unsigned*)(rows + (size_t)t * KCAP);
        unsigned rw = wrow[lane & 31];
        int deg = cnt[(size_t)t * cstr];
        deg = __builtin_amdgcn_readfirstlane(deg);
        deg = min(deg, KCAP);

        // target row (regular loads; compiler tracks their vmcnt)
        size_t trow = (size_t)t << 8;
        uint4 t0 = *reinterpret_cast<const uint4*>(xb + trow + coff);
        uint4 t1 = *reinterpret_cast<const uint4*>(xb + trow + 128 + coff);

        // slot s ushort: word s>>1 of the row, half s&1
        auto nid = [&](int s) -> int {
            unsigned wv = __shfl(rw, (lane & 32) | (s >> 1));
            return (int)((s & 1) ? (wv >> 16) : (wv & 0xFFFFu));
        };

        // stage up to 3 chunks (24 neighbors) into LDS, ONCE per node
        if (deg > 0) {
            int kmax = (min(deg, 24) + 7) >> 3;
            for (int k = 0; k < kmax; ++k) {
                int s  = e8 + 8 * k;
                int sl = (s < deg) ? s : 0;          // clamp: dummy slot 0
                int off = nid(sl) << 8;
                const char* ga = xb + off + coff;    // a-half, lane's 16B
                const char* gb = ga + 128;           // b-half
                __builtin_amdgcn_global_load_lds(
                    (const __attribute__((address_space(1))) unsigned int*)ga,
                    (__attribute__((address_space(3))) unsigned int*)
                        (wbase + k * 2048 + (lane << 4)), 16, 0, 0);
                __builtin_amdgcn_global_load_lds(
                    (const __attribute__((address_space(1))) unsigned int*)gb,
                    (__attribute__((address_space(3))) unsigned int*)
                        (wbase + k * 2048 + 1024 + (lane << 4)), 16, 0, 0);
            }
        }

        // normalize target capsule while staging flies (packed tw[] + sc)
        unsigned tw[8] = {t0.x, t0.y, t0.z, t0.w, t1.x, t1.y, t1.z, t1.w};
        float ss = 0.0f;
        #pragma unroll
        for (int q = 0; q < 8; ++q) {
            float xl = bits_lo(tw[q]), xh = bits_hi(tw[q]);
            ss = fmaf(xl, xl, ss);
            ss = fmaf(xh, xh, ss);
        }
        float sc = __builtin_amdgcn_rsqf(fmaxf(ss, 1e-24f));
        float u[DPC];
        #pragma unroll
        for (int q = 0; q < 8; ++q) {
            u[2*q]   = bits_lo(tw[q]) * sc;
            u[2*q+1] = bits_hi(tw[q]) * sc;
        }

        // drain the async LDS writes (compiler doesn't track the builtin)
        asm volatile("s_waitcnt vmcnt(0)" ::: "memory");

        for (int it = 0; it < 3; ++it) {
            // stop LDS-load CSE across iterations (would rebuild the 24-reg
            // live set and spill, as in r1/r3)
            asm volatile("" ::: "memory");

            float acc[DPC];
            #pragma unroll
            for (int j = 0; j < DPC; ++j) acc[j] = 0.0f;

            #pragma unroll
            for (int k = 0; k < 3; ++k) {
                if (deg > 8 * k) {
                    uint4 a = *reinterpret_cast<const uint4*>(
                        wbase + k * 2048 + (lane << 4));
                    uint4 b = *reinterpret_cast<const uint4*>(
                        wbase + k * 2048 + 1024 + (lane << 4));
                    proc_pk(a, b, 8 * k + e8 < deg, u, acc);
                }
            }
            if (deg > 24) {                  // rare tail: stream per iteration
                for (int base = 24; base < deg; base += 8) {
                    int s  = base + e8;
                    int sl = (s < deg) ? s : 0;
                    int off = nid(sl) << 8;
                    uint4 a = *reinterpret_cast<const uint4*>(xb + off + coff);
                    uint4 b = *reinterpret_cast<const uint4*>(xb + off + 128 + coff);
                    proc_pk(a, b, s < deg, u, acc);
                }
            }

            // reduce across the 8 edge slots (lane bits 3..5)
            #pragma unroll
            for (int j = 0; j < DPC; ++j) {
                acc[j] += __shfl_xor(acc[j], 8);
                acc[j] += __shfl_xor(acc[j], 16);
                acc[j] += __shfl_xor(acc[j], 32);
            }
            // residual + per-capsule l2norm; xt recomputed from tw,sc
            float s2 = 0.0f;
            #pragma unroll
            for (int q = 0; q < 8; ++q) {
                float xl = bits_lo(tw[q]) * sc;
                float xh = bits_hi(tw[q]) * sc;
                u[2*q]   = acc[2*q]   + xl;
                u[2*q+1] = acc[2*q+1] + xh;
                s2 = fmaf(u[2*q],   u[2*q],   s2);
                s2 = fmaf(u[2*q+1], u[2*q+1], s2);
            }
            float sc2 = __builtin_amdgcn_rsqf(fmaxf(s2, 1e-24f));
            #pragma unroll
            for (int j = 0; j < DPC; ++j) u[j] *= sc2;
        }

        if (e8 == 0) {  // lanes 0..7 cover the full 512 B fp32 output row
            float* dst = u_out + (size_t)t * DF + c * DPC;
            #pragma unroll
            for (int j = 0; j < DPC; j += 4)
                *reinterpret_cast<float4*>(dst + j) =
                    make_float4(u[j], u[j+1], u[j+2], u[j+3]);
        }
    }
}

extern "C" void kernel_launch(void* const* d_in, const int* in_sizes, int n_in,
                              void* d_out, int out_size, void* d_ws, size_t ws_size,
                              hipStream_t stream) {
    const void* x  = d_in[0];
    const int*  ei = (const int*)d_in[1];
    const int n_nodes = in_sizes[0] / DF;        // 50000
    const int n_edges = in_sizes[1] / 2;         // 800000
    const size_t NC = (size_t)n_nodes * DF;

    // ws layout: xcb bf16 [12.8MB] | slot rows [6.4MB] | flags | cnt [<=6.4MB]
    unsigned char* p = (unsigned char*)d_ws;
    unsigned int*   xcb  = (unsigned int*)p;   p += NC * 2;
    unsigned short* rows = (unsigned short*)p; p += (size_t)n_nodes * KCAP * 2;
    int*            flags = (int*)p;           p += 128;
    int*            cnt  = (int*)p;
    size_t used  = (size_t)(p - (unsigned char*)d_ws);
    size_t avail = (ws_size > used) ? (ws_size - used) : 0;
    int cstr = 32;  // ints between counts: 128B = atomic-only line per node
    while (cstr > 1 && (size_t)n_nodes * cstr * sizeof(int) > avail) cstr >>= 1;
    int zwords = n_nodes * cstr;

    float* u_out = (float*)d_out;

    k_detect_zero<<<NB_ZERO, 256, 0, stream>>>(
        (const unsigned int*)x, (const unsigned int*)ei, flags, cnt, zwords);
    k_bucket<<<NB_BKT, 256, 0, stream>>>(ei, cnt, cstr, rows, flags,
                                         n_nodes, n_edges);
    k_xc<<<NB_XC, 256, 0, stream>>>(x, xcb, flags, n_nodes);
    k_route<<<NB_ROUTE, 256, 0, stream>>>(rows, xcb, cnt, cstr, u_out, n_nodes);
}